// Round 1
// baseline (24.664 us; speedup 1.0000x reference)
//
#include <hip/hip_runtime.h>
#include <hip/hip_bf16.h>

typedef __attribute__((ext_vector_type(8))) short short8;
typedef __attribute__((ext_vector_type(4))) float f32x4;

#define NROW 16   // rows per block of the fused kernel

__device__ __forceinline__ unsigned short f2bf(float f) {
    unsigned int u = __builtin_bit_cast(unsigned int, f);
    u += 0x7FFFu + ((u >> 16) & 1u);   // RNE round to bf16
    return (unsigned short)(u >> 16);
}

// K0: convert W1 (128x768), W2 (64x128), W3 (32x64) f32 -> bf16 into workspace.
// Layout in ws (ushort): W1b @ 0 (98304), W2b @ 98304 (8192), W3b @ 106496 (2048).
__global__ __launch_bounds__(256) void cvt_weights(
    const float* __restrict__ W1, const float* __restrict__ W2,
    const float* __restrict__ W3, unsigned short* __restrict__ wsb)
{
    int i = blockIdx.x * 256 + threadIdx.x;
    if (i < 98304)        wsb[i] = f2bf(W1[i]);
    else if (i < 106496)  wsb[i] = f2bf(W2[i - 98304]);
    else if (i < 108544)  wsb[i] = f2bf(W3[i - 106496]);
}

// K1: fused. 256 blocks x 512 threads. Block handles 16 rows.
// waves 0-3: MLP via MFMA (z1: 16x128, z2: 16x64, z3: 16x32 -> s=||z3||^2)
// waves 4-7: stream Xp1/Xp2, per-row dot & squared norms
__global__ __launch_bounds__(512) void fused_qwn(
    const float* __restrict__ X,
    const unsigned short* __restrict__ wsb,
    const float* __restrict__ b1,
    const float* __restrict__ b2,
    const float* __restrict__ b3,
    float* __restrict__ out)
{
    __shared__ __align__(16) unsigned short z1_lds[NROW * 136]; // 16x128 bf16, stride 136 (conflict-free)
    __shared__ __align__(16) unsigned short z2_lds[NROW * 72];  // 16x64  bf16, stride 72
    __shared__ float s_lds[2][NROW];
    __shared__ float d_lds[NROW], n1_lds[NROW], n2_lds[NROW];

    const int tid  = threadIdx.x;
    const int wid  = tid >> 6;
    const int lane = tid & 63;
    const int l15  = lane & 15;
    const int l4   = lane >> 4;
    const int row0 = blockIdx.x * NROW;

    const unsigned short* W1b = wsb;
    const unsigned short* W2b = wsb + 98304;
    const unsigned short* W3b = wsb + 106496;

    if (wid < 4) {
        // ---------------- GEMM1: z1 = relu(Xq @ W1^T + b1) ----------------
        // M=16 (block rows), N=128 (wave w owns cols [32w, 32w+32)), K=768.
        // A-frag: lane reads Xq[row0 + l15][k0 + l4*8 + j] (f32 -> bf16 in reg)
        // B-frag: lane reads W1b[n][k0 + l4*8 + j], n = 32*wid (+16) + l15
        f32x4 acc0 = {0.f, 0.f, 0.f, 0.f};
        f32x4 acc1 = {0.f, 0.f, 0.f, 0.f};
        const float* arow = X + (size_t)(row0 + l15) * 2304 + l4 * 8;
        const unsigned short* bp0 = W1b + (size_t)(32 * wid + l15) * 768 + l4 * 8;
        const unsigned short* bp1 = bp0 + 16 * 768;
#pragma unroll 6
        for (int k0 = 0; k0 < 768; k0 += 32) {
            const float4* ap = (const float4*)(arow + k0);
            float4 a0 = ap[0];
            float4 a1 = ap[1];
            short8 av;
            av[0] = (short)f2bf(a0.x); av[1] = (short)f2bf(a0.y);
            av[2] = (short)f2bf(a0.z); av[3] = (short)f2bf(a0.w);
            av[4] = (short)f2bf(a1.x); av[5] = (short)f2bf(a1.y);
            av[6] = (short)f2bf(a1.z); av[7] = (short)f2bf(a1.w);
            short8 bv0 = *(const short8*)(bp0 + k0);
            short8 bv1 = *(const short8*)(bp1 + k0);
            acc0 = __builtin_amdgcn_mfma_f32_16x16x32_bf16(av, bv0, acc0, 0, 0, 0);
            acc1 = __builtin_amdgcn_mfma_f32_16x16x32_bf16(av, bv1, acc1, 0, 0, 0);
        }
        // epilogue: bias+relu, write z1 tile to LDS as bf16
        float bb0 = b1[32 * wid + l15];
        float bb1 = b1[32 * wid + 16 + l15];
#pragma unroll
        for (int r = 0; r < 4; ++r) {
            int orow = 4 * l4 + r;                 // D layout: row=(lane>>4)*4+reg, col=lane&15
            z1_lds[orow * 136 + 32 * wid + l15]      = f2bf(fmaxf(acc0[r] + bb0, 0.f));
            z1_lds[orow * 136 + 32 * wid + 16 + l15] = f2bf(fmaxf(acc1[r] + bb1, 0.f));
        }
    } else {
        // ---------------- Xp phase: wave q handles rows 4q..4q+3 ----------------
        const int q = wid - 4;
        float4 v1[4][3], v2[4][3];
#pragma unroll
        for (int i = 0; i < 4; ++i) {
            const float4* p1 = (const float4*)(X + (size_t)(row0 + 4 * q + i) * 2304 + 768);
            const float4* p2 = (const float4*)(X + (size_t)(row0 + 4 * q + i) * 2304 + 1536);
#pragma unroll
            for (int c = 0; c < 3; ++c) {
                v1[i][c] = p1[lane + 64 * c];
                v2[i][c] = p2[lane + 64 * c];
            }
        }
#pragma unroll
        for (int i = 0; i < 4; ++i) {
            float dd = 0.f, aa = 0.f, bb = 0.f;
#pragma unroll
            for (int c = 0; c < 3; ++c) {
                float4 x = v1[i][c], y = v2[i][c];
                dd += x.x * y.x + x.y * y.y + x.z * y.z + x.w * y.w;
                aa += x.x * x.x + x.y * x.y + x.z * x.z + x.w * x.w;
                bb += y.x * y.x + y.y * y.y + y.z * y.z + y.w * y.w;
            }
#pragma unroll
            for (int m = 1; m < 64; m <<= 1) {
                dd += __shfl_xor(dd, m);
                aa += __shfl_xor(aa, m);
                bb += __shfl_xor(bb, m);
            }
            if (lane == 0) {
                d_lds[4 * q + i]  = dd;
                n1_lds[4 * q + i] = aa;
                n2_lds[4 * q + i] = bb;
            }
        }
    }
    __syncthreads();

    if (wid < 4) {
        // ---------------- z2 = relu(z1 @ W2^T + b2): M=16, N=64 (wave w: n-tile w), K=128
        f32x4 acc = {0.f, 0.f, 0.f, 0.f};
#pragma unroll
        for (int ks = 0; ks < 4; ++ks) {
            short8 a = *(const short8*)&z1_lds[l15 * 136 + ks * 32 + l4 * 8];
            short8 b = *(const short8*)(W2b + (16 * wid + l15) * 128 + ks * 32 + l4 * 8);
            acc = __builtin_amdgcn_mfma_f32_16x16x32_bf16(a, b, acc, 0, 0, 0);
        }
        float bb = b2[16 * wid + l15];
#pragma unroll
        for (int r = 0; r < 4; ++r)
            z2_lds[(4 * l4 + r) * 72 + 16 * wid + l15] = f2bf(fmaxf(acc[r] + bb, 0.f));
    }
    __syncthreads();

    if (wid < 2) {
        // ---------------- z3 = relu(z2 @ W3^T + b3): M=16, N=32 (waves 0,1), K=64
        f32x4 acc = {0.f, 0.f, 0.f, 0.f};
#pragma unroll
        for (int ks = 0; ks < 2; ++ks) {
            short8 a = *(const short8*)&z2_lds[l15 * 72 + ks * 32 + l4 * 8];
            short8 b = *(const short8*)(W3b + (16 * wid + l15) * 64 + ks * 32 + l4 * 8);
            acc = __builtin_amdgcn_mfma_f32_16x16x32_bf16(a, b, acc, 0, 0, 0);
        }
        float bb = b3[16 * wid + l15];
        float sv[4];
#pragma unroll
        for (int r = 0; r < 4; ++r) {
            float v = fmaxf(acc[r] + bb, 0.f);
            sv[r] = v * v;
        }
        // reduce across the 16 column-lanes (butterfly over lane bits 0..3)
#pragma unroll
        for (int m = 1; m < 16; m <<= 1) {
#pragma unroll
            for (int r = 0; r < 4; ++r) sv[r] += __shfl_xor(sv[r], m);
        }
        if (l15 == 0) {
#pragma unroll
            for (int r = 0; r < 4; ++r) s_lds[wid][4 * l4 + r] = sv[r];
        }
    }
    __syncthreads();

    // ---------------- combine: out = s*d / max(s*sqrt(n1s*n2s), eps)
    if (tid < NROW) {
        float s   = s_lds[0][tid] + s_lds[1][tid];
        float den = fmaxf(s * sqrtf(n1_lds[tid] * n2_lds[tid]), 1e-8f);
        out[row0 + tid] = (s * d_lds[tid]) / den;
    }
}

extern "C" void kernel_launch(void* const* d_in, const int* in_sizes, int n_in,
                              void* d_out, int out_size, void* d_ws, size_t ws_size,
                              hipStream_t stream)
{
    (void)in_sizes; (void)n_in; (void)out_size; (void)ws_size;
    const float* X  = (const float*)d_in[0];
    const float* W1 = (const float*)d_in[1];
    const float* b1 = (const float*)d_in[2];
    const float* W2 = (const float*)d_in[3];
    const float* b2 = (const float*)d_in[4];
    const float* W3 = (const float*)d_in[5];
    const float* b3 = (const float*)d_in[6];
    unsigned short* wsb = (unsigned short*)d_ws;

    cvt_weights<<<dim3(424), dim3(256), 0, stream>>>(W1, W2, W3, wsb);
    fused_qwn<<<dim3(256), dim3(512), 0, stream>>>(X, wsb, b1, b2, b3, (float*)d_out);
}

// Round 2
// 24.038 us; speedup vs baseline: 1.0260x; 1.0260x over previous
//
#include <hip/hip_runtime.h>
#include <hip/hip_bf16.h>

typedef __attribute__((ext_vector_type(8))) short short8;
typedef __attribute__((ext_vector_type(4))) float f32x4;

#define NROW 16   // rows per block

// bf16 truncation (round-toward-zero). Safe here: the MLP result s = ||z3||^2
// cancels exactly in out = s*d / max(s*sqrt(n1*n2), eps); only d,n1,n2 (pure
// f32 from raw X) reach the output, so MLP rounding is irrelevant.
__device__ __forceinline__ unsigned int bfhi(float f) {
    return __builtin_bit_cast(unsigned int, f);
}
__device__ __forceinline__ unsigned int pack2(float lo, float hi) {
    return (bfhi(lo) >> 16) | (bfhi(hi) & 0xffff0000u);
}
__device__ __forceinline__ short8 pack_bf8(float4 a, float4 b) {
    uint4 u;
    u.x = pack2(a.x, a.y);
    u.y = pack2(a.z, a.w);
    u.z = pack2(b.x, b.y);
    u.w = pack2(b.z, b.w);
    return __builtin_bit_cast(short8, u);
}

// Single fused kernel. 256 blocks x 512 threads (8 waves), 16 rows/block.
// Phase 1: all 8 waves stream X coalesced: Xq -> LDS bf16; Xp1,Xp2 -> dot/norms.
// Phase 2: GEMM1 (M=16,N=128,K=768) split across 8 waves, A from LDS, B = W1
//          f32 from L2 with in-register truncation to bf16.
// Phase 3/4: z2, z3 via MFMA; s = ||z3||^2. Combine.
__global__ __launch_bounds__(512) void fused_qwn(
    const float* __restrict__ X,
    const float* __restrict__ W1, const float* __restrict__ b1,
    const float* __restrict__ W2, const float* __restrict__ b2,
    const float* __restrict__ W3, const float* __restrict__ b3,
    float* __restrict__ out)
{
    __shared__ __align__(16) unsigned short xq[NROW][776];     // 16x768 bf16, stride 776 (2-way max)
    __shared__ __align__(16) unsigned short z1_lds[NROW][136];
    __shared__ __align__(16) unsigned short z2_lds[NROW][72];
    __shared__ float s_lds[2][NROW];
    __shared__ float d_lds[NROW], n1_lds[NROW], n2_lds[NROW];

    const int tid  = threadIdx.x;
    const int wid  = tid >> 6;
    const int lane = tid & 63;
    const int l15  = lane & 15;
    const int l4   = lane >> 4;
    const int row0 = blockIdx.x * NROW;

    // ---------------- Phase 1: coalesced stream of X ----------------
    {
        const int r = tid >> 5;     // 0..15 (row)
        const int c = tid & 31;     // 0..31 (column slot)
        const float4* base = (const float4*)(X + (size_t)(row0 + r) * 2304);
        float dd = 0.f, aa = 0.f, bb = 0.f;
#pragma unroll
        for (int m = 0; m < 6; ++m) {
            const int j = c + 32 * m;          // float4 index in [0,192)
            float4 q  = base[j];               // Xq
            float4 p1 = base[192 + j];         // Xp1
            float4 p2 = base[384 + j];         // Xp2
            uint2 qb;
            qb.x = pack2(q.x, q.y);
            qb.y = pack2(q.z, q.w);
            *(uint2*)&xq[r][4 * j] = qb;
            dd += p1.x * p2.x + p1.y * p2.y + p1.z * p2.z + p1.w * p2.w;
            aa += p1.x * p1.x + p1.y * p1.y + p1.z * p1.z + p1.w * p1.w;
            bb += p2.x * p2.x + p2.y * p2.y + p2.z * p2.z + p2.w * p2.w;
        }
        // reduce across the 32 threads of this row (lane bits 0..4)
#pragma unroll
        for (int m = 1; m < 32; m <<= 1) {
            dd += __shfl_xor(dd, m);
            aa += __shfl_xor(aa, m);
            bb += __shfl_xor(bb, m);
        }
        if ((lane & 31) == 0) {
            d_lds[r]  = dd;
            n1_lds[r] = aa;
            n2_lds[r] = bb;
        }
    }
    __syncthreads();

    // ---------------- Phase 2: GEMM1 z1 = relu(Xq @ W1^T + b1) ----------------
    // 8 waves x 16 N-cols each. A from LDS, B from global f32 (L2-resident).
    {
        f32x4 acc = {0.f, 0.f, 0.f, 0.f};
        const float* bp = W1 + (size_t)(16 * wid + l15) * 768 + l4 * 8;
#pragma unroll 4
        for (int k0 = 0; k0 < 768; k0 += 32) {
            short8 a = *(const short8*)&xq[l15][k0 + l4 * 8];
            float4 w0 = *(const float4*)(bp + k0);
            float4 w1 = *(const float4*)(bp + k0 + 4);
            acc = __builtin_amdgcn_mfma_f32_16x16x32_bf16(a, pack_bf8(w0, w1), acc, 0, 0, 0);
        }
        float bb = b1[16 * wid + l15];
#pragma unroll
        for (int r = 0; r < 4; ++r) {
            float v = fmaxf(acc[r] + bb, 0.f);
            z1_lds[4 * l4 + r][16 * wid + l15] = (unsigned short)(bfhi(v) >> 16);
        }
    }
    __syncthreads();

    // ---------------- Phase 3: z2 = relu(z1 @ W2^T + b2), M=16,N=64,K=128 ----------------
    if (wid < 4) {
        f32x4 acc = {0.f, 0.f, 0.f, 0.f};
        const float* bp = W2 + (size_t)(16 * wid + l15) * 128 + l4 * 8;
#pragma unroll
        for (int ks = 0; ks < 4; ++ks) {
            short8 a = *(const short8*)&z1_lds[l15][ks * 32 + l4 * 8];
            float4 w0 = *(const float4*)(bp + ks * 32);
            float4 w1 = *(const float4*)(bp + ks * 32 + 4);
            acc = __builtin_amdgcn_mfma_f32_16x16x32_bf16(a, pack_bf8(w0, w1), acc, 0, 0, 0);
        }
        float bb = b2[16 * wid + l15];
#pragma unroll
        for (int r = 0; r < 4; ++r) {
            float v = fmaxf(acc[r] + bb, 0.f);
            z2_lds[4 * l4 + r][16 * wid + l15] = (unsigned short)(bfhi(v) >> 16);
        }
    }
    __syncthreads();

    // ---------------- Phase 4: z3 = relu(z2 @ W3^T + b3), M=16,N=32,K=64; s=||z3||^2 ----------------
    if (wid < 2) {
        f32x4 acc = {0.f, 0.f, 0.f, 0.f};
        const float* bp = W3 + (size_t)(16 * wid + l15) * 64 + l4 * 8;
#pragma unroll
        for (int ks = 0; ks < 2; ++ks) {
            short8 a = *(const short8*)&z2_lds[l15][ks * 32 + l4 * 8];
            float4 w0 = *(const float4*)(bp + ks * 32);
            float4 w1 = *(const float4*)(bp + ks * 32 + 4);
            acc = __builtin_amdgcn_mfma_f32_16x16x32_bf16(a, pack_bf8(w0, w1), acc, 0, 0, 0);
        }
        float bb = b3[16 * wid + l15];
        float sv[4];
#pragma unroll
        for (int r = 0; r < 4; ++r) {
            float v = fmaxf(acc[r] + bb, 0.f);
            sv[r] = v * v;
        }
#pragma unroll
        for (int m = 1; m < 16; m <<= 1) {
#pragma unroll
            for (int r = 0; r < 4; ++r) sv[r] += __shfl_xor(sv[r], m);
        }
        if (l15 == 0) {
#pragma unroll
            for (int r = 0; r < 4; ++r) s_lds[wid][4 * l4 + r] = sv[r];
        }
    }
    __syncthreads();

    // ---------------- Combine ----------------
    if (tid < NROW) {
        float s   = s_lds[0][tid] + s_lds[1][tid];
        float den = fmaxf(s * sqrtf(n1_lds[tid] * n2_lds[tid]), 1e-8f);
        out[row0 + tid] = (s * d_lds[tid]) / den;
    }
}

extern "C" void kernel_launch(void* const* d_in, const int* in_sizes, int n_in,
                              void* d_out, int out_size, void* d_ws, size_t ws_size,
                              hipStream_t stream)
{
    (void)in_sizes; (void)n_in; (void)out_size; (void)d_ws; (void)ws_size;
    const float* X  = (const float*)d_in[0];
    const float* W1 = (const float*)d_in[1];
    const float* b1 = (const float*)d_in[2];
    const float* W2 = (const float*)d_in[3];
    const float* b2 = (const float*)d_in[4];
    const float* W3 = (const float*)d_in[5];
    const float* b3 = (const float*)d_in[6];

    fused_qwn<<<dim3(256), dim3(512), 0, stream>>>(X, W1, b1, W2, b2, W3, b3, (float*)d_out);
}